// Round 5
// baseline (375.325 us; speedup 1.0000x reference)
//
#include <hip/hip_runtime.h>
#include <hip/hip_bf16.h>

#define E_TOT 160000
#define NN    10000
#define EPB   32      // edges per block (MFMA M-tiles of 16; vectors use 96 = 3*32 rows)

typedef unsigned short ushortT;
typedef unsigned int   uintT;
typedef __attribute__((ext_vector_type(8))) short short8;
typedef __attribute__((ext_vector_type(4))) float f32x4;

__device__ __forceinline__ float sigmoidf_(float x) { return 1.0f / (1.0f + __expf(-x)); }
__device__ __forceinline__ float siluf_(float x) { return x * sigmoidf_(x); }

__device__ __forceinline__ ushortT f2b(float f) {
    union { float f; uintT u; } x; x.f = f;
    uintT r = x.u + 0x7fffu + ((x.u >> 16) & 1u);
    return (ushortT)(r >> 16);
}
__device__ __forceinline__ float b2f(ushortT h) {
    union { uintT u; float f; } x; x.u = ((uintT)h) << 16; return x.f;
}
// packed pair f32x2 -> bf16x2 (HW v_cvt_pk_bf16_f32 on gfx950 via hip header)
__device__ __forceinline__ uintT pk2(float lo, float hi) {
    union { __hip_bfloat162 h; uintT u; } cv;
    cv.h = __float22bfloat162_rn(make_float2(lo, hi));
    return cv.u;
}
// 8 consecutive fp32 -> bf16 MFMA A-fragment
__device__ __forceinline__ short8 ldfrag(const float* p) {
    const float4 x = ((const float4*)p)[0];
    const float4 y = ((const float4*)p)[1];
    union { uintT u[4]; short8 s; } r;
    r.u[0] = pk2(x.x, x.y); r.u[1] = pk2(x.z, x.w);
    r.u[2] = pk2(y.x, y.y); r.u[3] = pk2(y.z, y.w);
    return r.s;
}

// ---- workspace layout (ushort offsets) ----
#define OFF_W1SO 0
#define OFF_W2SO 45056
#define OFF_W1DF 65536
#define OFF_W1G  68608
#define OFF_W1UP 70656
#define OFF_W2DF 71680
#define OFF_W2G  72704
#define OFF_W2UP 74752
// total 75264 ushorts

// Prep: weight transposes to bf16 + zero d_out (fused; one fewer dispatch).
__global__ __launch_bounds__(256) void prep_kernel(
    const float* __restrict__ W1so, const float* __restrict__ W2so,
    const float* __restrict__ W1d,  const float* __restrict__ W1f,
    const float* __restrict__ W1g,  const float* __restrict__ W1up,
    const float* __restrict__ W2d,  const float* __restrict__ W2f,
    const float* __restrict__ W2g,  const float* __restrict__ W2up,
    ushortT* __restrict__ ws, float* __restrict__ out)
{
    int i = blockIdx.x * 256 + threadIdx.x;    // grid 294*256 = 75264 exactly
    // zero d_out: 1,760,000 floats = 440,000 float4
    float4* o4 = (float4*)out;
    #pragma unroll
    for (int k = 0; k < 6; ++k) {
        int z = i + k * 75264;
        if (z < 440000) o4[z] = make_float4(0.f, 0.f, 0.f, 0.f);
    }
    if (i < OFF_W2SO) {                        // W1soT [n=128][k=352], k<333 real
        int n = i / 352, k = i - n * 352;
        ws[i] = (k < 333) ? f2b(W1so[k * 128 + n]) : (ushortT)0;
    } else if (i < OFF_W1DF) {                 // W2soT [128][160], k<153 real
        int j = i - OFF_W2SO, n = j / 160, k = j - n * 160;
        ws[i] = (k < 153) ? f2b(W2so[k * 128 + n]) : (ushortT)0;
    } else if (i < OFF_W1G) {                  // W1dfT [48][64]: n<36 Wd, 36..38 Wf
        int j = i - OFF_W1DF, n = j / 64, k = j - n * 64;
        float v = 0.f;
        if (k < 36) { if (n < 36) v = W1d[k * 36 + n]; else if (n < 39) v = W1f[k * 3 + (n - 36)]; }
        ws[i] = f2b(v);
    } else if (i < OFF_W1UP) {                 // W1gT [16][128]
        int j = i - OFF_W1G, n = j / 128, k = j - n * 128;
        ws[i] = f2b(W1g[k * 16 + n]);
    } else if (i < OFF_W2DF) {                 // W1upT [16][64], k<36 real
        int j = i - OFF_W1UP, n = j / 64, k = j - n * 64;
        ws[i] = (k < 36) ? f2b(W1up[k * 16 + n]) : (ushortT)0;
    } else if (i < OFF_W2G) {                  // W2dfT [32][32]: n<16 Wd, 16..18 Wf; k<16
        int j = i - OFF_W2DF, n = j / 32, k = j - n * 32;
        float v = 0.f;
        if (k < 16) { if (n < 16) v = W2d[k * 16 + n]; else if (n < 19) v = W2f[k * 3 + (n - 16)]; }
        ws[i] = f2b(v);
    } else if (i < OFF_W2UP) {                 // W2gT [16][128]
        int j = i - OFF_W2G, n = j / 128, k = j - n * 128;
        ws[i] = f2b(W2g[k * 16 + n]);
    } else {                                   // W2upT [16][32], k<16 real
        int j = i - OFF_W2UP, n = j / 32, k = j - n * 32;
        ws[i] = (k < 16) ? f2b(W2up[k * 16 + n]) : (ushortT)0;
    }
}

#define MFMA(a, b, c) __builtin_amdgcn_mfma_f32_16x16x32_bf16((a), (b), (c), 0, 0, 0)

// All contractions on MFMA; Phase-D A-operand direct from global (no merged1 LDS).
// LDS 46,592 B -> 3 blocks/CU.
__global__ __launch_bounds__(256, 3) void edge_kernel(
    const float* __restrict__ node_s, const float* __restrict__ node_v,
    const float* __restrict__ edge_s, const float* __restrict__ edge_v,
    const float* __restrict__ frames,
    const float* __restrict__ b1so, const float* __restrict__ b1g,
    const float* __restrict__ b2so, const float* __restrict__ b2g,
    const float* __restrict__ attW, const float* __restrict__ attb,
    const ushortT* __restrict__ wsc,
    const void* __restrict__ eidx, float* __restrict__ out)
{
    const ushortT* W1T   = wsc + OFF_W1SO;
    const ushortT* W2T   = wsc + OFF_W2SO;
    const ushortT* W1dfT = wsc + OFF_W1DF;
    const ushortT* W1gT  = wsc + OFF_W1G;
    const ushortT* W1upT = wsc + OFF_W1UP;
    const ushortT* W2dfT = wsc + OFF_W2DF;
    const ushortT* W2gT  = wsc + OFF_W2G;
    const ushortT* W2upT = wsc + OFF_W2UP;

    // ---- LDS overlay map (bytes), total 46592 ----
    // R1 [0..17408): gbuf f32[32][16] @0, v1A bf16[96][40] @2048, vhid2A bf16[96][40] @9728
    //                normbuf bf16[32][72] aliased @0 (live A/C -> D only)
    // R2 [17408..31232): mvA bf16[96][72] (A->B) | m2 bf16[32][168] (D-epi->L)
    // R3 [31232..45056): vhidA bf16[96][72] (B->E2) | s2s bf16[32][136] (I->L)
    // tail: fr f32[32][9] @45056, attn @46208, rowb @46336, colb @46464
    __shared__ __align__(16) char smem[46592];
    float*   gbuf    = (float*)smem;
    ushortT* normbuf = (ushortT*)smem;
    ushortT* v1A     = (ushortT*)(smem + 2048);
    ushortT* vhid2A  = (ushortT*)(smem + 9728);
    ushortT* mvA     = (ushortT*)(smem + 17408);
    ushortT* m2      = (ushortT*)(smem + 17408);
    ushortT* vhidA   = (ushortT*)(smem + 31232);
    ushortT* s2s     = (ushortT*)(smem + 31232);
    float*   fr      = (float*)(smem + 45056);
    float*   attn    = (float*)(smem + 46208);
    int*     rowb    = (int*)(smem + 46336);
    int*     colb    = (int*)(smem + 46464);

    const int t  = threadIdx.x;
    const int eg = blockIdx.x * EPB;
    const int w  = t >> 6, lane = t & 63, lq = lane >> 4, ln = lane & 15;

    // ---- index load, runtime int32/int64 detection ----
    {
        const int* pi = (const int*)eidx;
        const long long* pl = (const long long*)eidx;
        bool is64 = ((pi[1] | pi[3] | pi[5] | pi[7] |
                      pi[9] | pi[11] | pi[13] | pi[15]) == 0);
        if (t < EPB) {
            int r, c;
            if (is64) { r = (int)pl[eg + t]; c = (int)pl[E_TOT + eg + t]; }
            else      { r = pi[eg + t];      c = pi[E_TOT + eg + t];      }
            rowb[t] = r; colb[t] = c;
        }
    }
    __syncthreads();

    const int te = t >> 3, tj = t & 7;   // 8 threads per edge maps

    // ==== Phase A: vector gather + pads + frames + normbuf K-pad ====
    {
        const int nvr = rowb[te] * 48, nvc = colb[te] * 48, evb = (eg + te) * 12;
        #pragma unroll
        for (int k = 0; k < 14; ++k) {          // 108 items per edge, 8 threads
            int r = tj + k * 8;
            if (r < 108) {
                float v;
                if (r < 48)      v = node_v[nvr + r];
                else if (r < 60) v = edge_v[evb + (r - 48)];
                else             v = node_v[nvc + (r - 60)];
                int c = r / 3, sp = r - c * 3;   // small-const div
                mvA[(sp * 32 + te) * 72 + c] = f2b(v);
            }
        }
        #pragma unroll
        for (int k = 0; k < 2; ++k) {           // frames: 9 per edge
            int j = tj + k * 8;
            if (j < 9) fr[te * 9 + j] = frames[(eg + te) * 9 + j];
        }
        #pragma unroll
        for (int k = 0; k < 3; ++k) {           // normbuf cols 45..63 = 0
            int c = 45 + tj + k * 8;
            if (c < 64) normbuf[te * 72 + c] = 0;
        }
    }
    for (int i = t; i < 1344; i += 256) {       // mvA cols 36..63 = 0 (uint writes)
        int r = i / 14, cc = 36 + 2 * (i - r * 14);
        *(uintT*)(mvA + r * 72 + cc) = 0;
    }
    for (int i = t; i < 768; i += 256) {        // vhidA cols 48..63 = 0
        int r = i >> 3, cc = 48 + ((i & 7) << 1);
        *(uintT*)(vhidA + r * 72 + cc) = 0;
    }
    __syncthreads();

    // ==== Phase B: mvA[96][64] @ W1dfT[48][64] -> vhidA[96][48] (36..38 = vfr1) ====
    for (int u = w; u < 18; u += 4) {
        int mt = u / 3, nt = u - mt * 3;
        const ushortT* ap = mvA + (mt * 16 + ln) * 72 + lq * 8;
        const ushortT* bp = W1dfT + (nt * 16 + ln) * 64 + lq * 8;
        f32x4 acc = {0.f, 0.f, 0.f, 0.f};
        acc = MFMA(*(const short8*)ap,        *(const short8*)bp,        acc);
        acc = MFMA(*(const short8*)(ap + 32), *(const short8*)(bp + 32), acc);
        ushortT* op = vhidA + (mt * 16 + lq * 4) * 72 + nt * 16 + ln;
        op[0]   = f2b(acc[0]); op[72]  = f2b(acc[1]);
        op[144] = f2b(acc[2]); op[216] = f2b(acc[3]);
    }
    __syncthreads();

    // ==== Phase C: v_norm1 + local1 -> normbuf cols 0..44 ====
    {
        #pragma unroll
        for (int k = 0; k < 5; ++k) {
            int h = tj + k * 8;
            if (h < 36) {
                float a0 = b2f(vhidA[te * 72 + h]);
                float a1 = b2f(vhidA[(32 + te) * 72 + h]);
                float a2 = b2f(vhidA[(64 + te) * 72 + h]);
                normbuf[te * 72 + h] = f2b(sqrtf(fmaf(a0, a0, fmaf(a1, a1, fmaf(a2, a2, 1e-8f)))));
            }
        }
        for (int i = t; i < 288; i += 256) {    // local1: 9 per edge
            int e = i / 9, r = i - e * 9, a = r / 3, b = r - a * 3;
            float x = fr[e * 9 + b * 3 + 0] * b2f(vhidA[e * 72 + 36 + a])
                    + fr[e * 9 + b * 3 + 1] * b2f(vhidA[(32 + e) * 72 + 36 + a])
                    + fr[e * 9 + b * 3 + 2] * b2f(vhidA[(64 + e) * 72 + 36 + a]);
            normbuf[e * 72 + 36 + r] = f2b(x);
        }
    }
    __syncthreads();

    // ==== Phase D: s_out1 — A direct from global (k<288) + normbuf (k 288..351) ====
    {
        const int klq = lq * 8;
        const int e0 = ln, e1 = 16 + ln;
        const int r0 = rowb[e0] * 128, c0 = colb[e0] * 128;
        const int r1 = rowb[e1] * 128, c1 = colb[e1] * 128;
        const int eb0 = (eg + e0) * 32, eb1 = (eg + e1) * 32;
        f32x4 acc00 = {0,0,0,0}, acc01 = {0,0,0,0}, acc10 = {0,0,0,0}, acc11 = {0,0,0,0};
        const ushortT* b0p = W1T + (w * 32 + ln) * 352 + klq;
        const ushortT* b1p = W1T + (w * 32 + 16 + ln) * 352 + klq;
        #pragma unroll
        for (int ks = 0; ks < 9; ++ks) {
            const float *pa0, *pa1;
            if (ks < 4)       { pa0 = node_s + r0 + ks * 32 + klq;        pa1 = node_s + r1 + ks * 32 + klq; }
            else if (ks == 4) { pa0 = edge_s + eb0 + klq;                 pa1 = edge_s + eb1 + klq; }
            else              { pa0 = node_s + c0 + (ks - 5) * 32 + klq;  pa1 = node_s + c1 + (ks - 5) * 32 + klq; }
            short8 a0 = ldfrag(pa0);
            short8 a1 = ldfrag(pa1);
            short8 b0 = *(const short8*)(b0p + ks * 32);
            short8 b1 = *(const short8*)(b1p + ks * 32);
            acc00 = MFMA(a0, b0, acc00); acc01 = MFMA(a0, b1, acc01);
            acc10 = MFMA(a1, b0, acc10); acc11 = MFMA(a1, b1, acc11);
        }
        #pragma unroll
        for (int ks = 9; ks < 11; ++ks) {
            short8 a0 = *(const short8*)(normbuf + e0 * 72 + (ks - 9) * 32 + klq);
            short8 a1 = *(const short8*)(normbuf + e1 * 72 + (ks - 9) * 32 + klq);
            short8 b0 = *(const short8*)(b0p + ks * 32);
            short8 b1 = *(const short8*)(b1p + ks * 32);
            acc00 = MFMA(a0, b0, acc00); acc01 = MFMA(a0, b1, acc01);
            acc10 = MFMA(a1, b0, acc10); acc11 = MFMA(a1, b1, acc11);
        }
        const int n0 = w * 32 + ln, n1 = n0 + 16;
        float bi0 = b1so[n0], bi1 = b1so[n1];
        #pragma unroll
        for (int r = 0; r < 4; ++r) {
            int m0 = lq * 4 + r;
            m2[m0 * 168 + n0]        = f2b(siluf_(acc00[r] + bi0));
            m2[m0 * 168 + n1]        = f2b(siluf_(acc01[r] + bi1));
            m2[(16 + m0) * 168 + n0] = f2b(siluf_(acc10[r] + bi0));
            m2[(16 + m0) * 168 + n1] = f2b(siluf_(acc11[r] + bi1));
        }
    }
    __syncthreads();

    // ==== Phase E: E2 = vhidA @ W1upT (raw v1); E1 = s1 @ W1gT (gate1, waves 2-3) ====
    f32x4 e2a0 = {0,0,0,0}, e2a1 = {0,0,0,0};
    {
        {   // E2 unit 0: mt = w
            const ushortT* ap = vhidA + (w * 16 + ln) * 72 + lq * 8;
            const ushortT* bp = W1upT + ln * 64 + lq * 8;
            e2a0 = MFMA(*(const short8*)ap,        *(const short8*)bp,        e2a0);
            e2a0 = MFMA(*(const short8*)(ap + 32), *(const short8*)(bp + 32), e2a0);
        }
        if (w < 2) {   // E2 unit 1: mt = w+4
            const ushortT* ap = vhidA + ((w + 4) * 16 + ln) * 72 + lq * 8;
            const ushortT* bp = W1upT + ln * 64 + lq * 8;
            e2a1 = MFMA(*(const short8*)ap,        *(const short8*)bp,        e2a1);
            e2a1 = MFMA(*(const short8*)(ap + 32), *(const short8*)(bp + 32), e2a1);
        } else {       // E1: gate1, mt = w-2
            int mt = w - 2;
            const ushortT* ap = m2 + (mt * 16 + ln) * 168;
            const ushortT* bp = W1gT + ln * 128;
            f32x4 acc = {0,0,0,0};
            #pragma unroll
            for (int ks = 0; ks < 4; ++ks)
                acc = MFMA(*(const short8*)(ap + ks * 32 + lq * 8),
                           *(const short8*)(bp + ks * 32 + lq * 8), acc);
            float bi = b1g[ln];
            #pragma unroll
            for (int r = 0; r < 4; ++r)
                gbuf[(mt * 16 + lq * 4 + r) * 16 + ln] = sigmoidf_(acc[r] + bi);
        }
        for (int i = t; i < 768; i += 256) {   // v1A cols 16..31 = 0 (G K-pad)
            int r = i >> 3, cc = 16 + ((i & 7) << 1);
            *(uintT*)(v1A + r * 40 + cc) = 0;
        }
    }
    __syncthreads();

    // ==== E2 epilogue: v1A = raw * gate1 ====
    {
        #pragma unroll
        for (int r = 0; r < 4; ++r) {
            int row = w * 16 + lq * 4 + r;
            v1A[row * 40 + ln] = f2b(e2a0[r] * gbuf[(row & 31) * 16 + ln]);
        }
        if (w < 2) {
            #pragma unroll
            for (int r = 0; r < 4; ++r) {
                int row = (w + 4) * 16 + lq * 4 + r;
                v1A[row * 40 + ln] = f2b(e2a1[r] * gbuf[(row & 31) * 16 + ln]);
            }
        }
    }
    __syncthreads();

    // ==== Phase G: v1A[96][32] @ W2dfT[32][32] -> vhid2A[96][32] (16..18 = vfr2) ====
    for (int u = w; u < 12; u += 4) {
        int mt = u >> 1, nt = u & 1;
        const ushortT* ap = v1A + (mt * 16 + ln) * 40 + lq * 8;
        const ushortT* bp = W2dfT + (nt * 16 + ln) * 32 + lq * 8;
        f32x4 acc = {0,0,0,0};
        acc = MFMA(*(const short8*)ap, *(const short8*)bp, acc);
        ushortT* op = vhid2A + (mt * 16 + lq * 4) * 40 + nt * 16 + ln;
        op[0]  = f2b(acc[0]); op[40]  = f2b(acc[1]);
        op[80] = f2b(acc[2]); op[120] = f2b(acc[3]);
    }
    __syncthreads();

    // ==== Phase H: norm2 + local2 + zero pad into m2 cols 128..159 ====
    {
        #pragma unroll
        for (int k = 0; k < 2; ++k) {           // 512 norm items
            int i = t + k * 256, e = i >> 4, h = i & 15;
            float a0 = b2f(vhid2A[e * 40 + h]);
            float a1 = b2f(vhid2A[(32 + e) * 40 + h]);
            float a2 = b2f(vhid2A[(64 + e) * 40 + h]);
            m2[e * 168 + 128 + h] = f2b(sqrtf(fmaf(a0, a0, fmaf(a1, a1, fmaf(a2, a2, 1e-8f)))));
        }
        for (int i = t; i < 288; i += 256) {    // local2
            int e = i / 9, r = i - e * 9, a = r / 3, b = r - a * 3;
            float x = fr[e * 9 + b * 3 + 0] * b2f(vhid2A[e * 40 + 16 + a])
                    + fr[e * 9 + b * 3 + 1] * b2f(vhid2A[(32 + e) * 40 + 16 + a])
                    + fr[e * 9 + b * 3 + 2] * b2f(vhid2A[(64 + e) * 40 + 16 + a]);
            m2[e * 168 + 144 + r] = f2b(x);
        }
        if (tj) m2[te * 168 + 152 + tj] = 0;    // cols 153..159 = 0
    }
    __syncthreads();

    // ==== Phase I: s_out2 = m2[32][160] @ W2soT -> s2s (silu) ====
    {
        f32x4 acc00 = {0,0,0,0}, acc01 = {0,0,0,0}, acc10 = {0,0,0,0}, acc11 = {0,0,0,0};
        const ushortT* a0p = m2 + ln * 168 + lq * 8;
        const ushortT* a1p = m2 + (16 + ln) * 168 + lq * 8;
        const ushortT* b0p = W2T + (w * 32 + ln) * 160 + lq * 8;
        const ushortT* b1p = W2T + (w * 32 + 16 + ln) * 160 + lq * 8;
        #pragma unroll
        for (int ks = 0; ks < 5; ++ks) {
            short8 a0 = *(const short8*)(a0p + ks * 32);
            short8 a1 = *(const short8*)(a1p + ks * 32);
            short8 b0 = *(const short8*)(b0p + ks * 32);
            short8 b1 = *(const short8*)(b1p + ks * 32);
            acc00 = MFMA(a0, b0, acc00); acc01 = MFMA(a0, b1, acc01);
            acc10 = MFMA(a1, b0, acc10); acc11 = MFMA(a1, b1, acc11);
        }
        const int n0 = w * 32 + ln, n1 = n0 + 16;
        float bi0 = b2so[n0], bi1 = b2so[n1];
        #pragma unroll
        for (int r = 0; r < 4; ++r) {
            int m0 = lq * 4 + r;
            s2s[m0 * 136 + n0]        = f2b(siluf_(acc00[r] + bi0));
            s2s[m0 * 136 + n1]        = f2b(siluf_(acc01[r] + bi1));
            s2s[(16 + m0) * 136 + n0] = f2b(siluf_(acc10[r] + bi0));
            s2s[(16 + m0) * 136 + n1] = f2b(siluf_(acc11[r] + bi1));
        }
    }
    __syncthreads();

    // ==== Phase J: J2 = vhid2A @ W2upT; J1 = s2 @ W2gT (gate2); attention ====
    f32x4 j2a0 = {0,0,0,0}, j2a1 = {0,0,0,0};
    {
        {   // J2 unit 0
            const ushortT* ap = vhid2A + (w * 16 + ln) * 40 + lq * 8;
            const ushortT* bp = W2upT + ln * 32 + lq * 8;
            j2a0 = MFMA(*(const short8*)ap, *(const short8*)bp, j2a0);
        }
        if (w < 2) {   // J2 unit 1
            const ushortT* ap = vhid2A + ((w + 4) * 16 + ln) * 40 + lq * 8;
            const ushortT* bp = W2upT + ln * 32 + lq * 8;
            j2a1 = MFMA(*(const short8*)ap, *(const short8*)bp, j2a1);
        } else {       // J1: gate2
            int mt = w - 2;
            const ushortT* ap = s2s + (mt * 16 + ln) * 136;
            const ushortT* bp = W2gT + ln * 128;
            f32x4 acc = {0,0,0,0};
            #pragma unroll
            for (int ks = 0; ks < 4; ++ks)
                acc = MFMA(*(const short8*)(ap + ks * 32 + lq * 8),
                           *(const short8*)(bp + ks * 32 + lq * 8), acc);
            float bi = b2g[ln];
            #pragma unroll
            for (int r = 0; r < 4; ++r)
                gbuf[(mt * 16 + lq * 4 + r) * 16 + ln] = sigmoidf_(acc[r] + bi);
        }
        // attention: sigmoid((s1+s2) . attW + b), 8 threads per edge
        {
            float sum = 0.f;
            int c0 = tj * 16;
            #pragma unroll
            for (int c = c0; c < c0 + 16; ++c)
                sum = fmaf(b2f(m2[te * 168 + c]) + b2f(s2s[te * 136 + c]), attW[c], sum);
            sum += __shfl_xor(sum, 4);
            sum += __shfl_xor(sum, 2);
            sum += __shfl_xor(sum, 1);
            if (tj == 0) attn[te] = sigmoidf_(sum + attb[0]);
        }
    }
    __syncthreads();

    // ==== J2 epilogue: v_final = v1 + raw_v2 * gate2 (in-place in v1A) ====
    {
        #pragma unroll
        for (int r = 0; r < 4; ++r) {
            int row = w * 16 + lq * 4 + r;
            float vfin = b2f(v1A[row * 40 + ln]) + j2a0[r] * gbuf[(row & 31) * 16 + ln];
            v1A[row * 40 + ln] = f2b(vfin);
        }
        if (w < 2) {
            #pragma unroll
            for (int r = 0; r < 4; ++r) {
                int row = (w + 4) * 16 + lq * 4 + r;
                float vfin = b2f(v1A[row * 40 + ln]) + j2a1[r] * gbuf[(row & 31) * 16 + ln];
                v1A[row * 40 + ln] = f2b(vfin);
            }
        }
    }
    __syncthreads();

    // ==== Phase L: scatter-add (8 threads per edge; branch uniform per k) ====
    {
        const int orow = rowb[te] * 176;
        const float at = attn[te];
        #pragma unroll
        for (int k = 0; k < 22; ++k) {
            int j = tj + k * 8;
            float val;
            if (j < 128) {
                val = (b2f(m2[te * 168 + j]) + b2f(s2s[te * 136 + j])) * at;
            } else {
                int r = j - 128, o = r / 3, sp = r - o * 3;
                val = b2f(v1A[(sp * 32 + te) * 40 + o]);
            }
            atomicAdd(&out[orow + j], val);
        }
    }
}

extern "C" void kernel_launch(void* const* d_in, const int* in_sizes, int n_in,
                              void* d_out, int out_size, void* d_ws, size_t ws_size,
                              hipStream_t stream) {
    const float* node_s = (const float*)d_in[0];
    const float* node_v = (const float*)d_in[1];
    const float* edge_s = (const float*)d_in[2];
    const float* edge_v = (const float*)d_in[3];
    const float* frames = (const float*)d_in[4];
    const float* W1d  = (const float*)d_in[5];
    const float* W1f  = (const float*)d_in[6];
    const float* W1so = (const float*)d_in[7];
    const float* b1so = (const float*)d_in[8];
    const float* W1up = (const float*)d_in[9];
    const float* W1g  = (const float*)d_in[10];
    const float* b1g  = (const float*)d_in[11];
    const float* W2d  = (const float*)d_in[12];
    const float* W2f  = (const float*)d_in[13];
    const float* W2so = (const float*)d_in[14];
    const float* b2so = (const float*)d_in[15];
    const float* W2up = (const float*)d_in[16];
    const float* W2g  = (const float*)d_in[17];
    const float* b2g  = (const float*)d_in[18];
    const float* attW = (const float*)d_in[19];
    const float* attb = (const float*)d_in[20];
    const void*  eidx = d_in[21];

    float* out = (float*)d_out;
    ushortT* ws16 = (ushortT*)d_ws;

    prep_kernel<<<294, 256, 0, stream>>>(W1so, W2so, W1d, W1f, W1g, W1up,
                                         W2d, W2f, W2g, W2up, ws16, out);

    edge_kernel<<<E_TOT / EPB, 256, 0, stream>>>(
        node_s, node_v, edge_s, edge_v, frames,
        b1so, b1g, b2so, b2g, attW, attb,
        (const ushortT*)ws16, eidx, out);
}